// Round 10
// baseline (1795.687 us; speedup 1.0000x reference)
//
#include <hip/hip_runtime.h>
#include <hip/hip_bf16.h>

// CALIBRATION ROUND R10 (pipeline = R8 logic, validated):
//  - probe_fma : 60k serial dependent v_fma chain, grid 512x256 (2 waves/SIMD)
//                => effective core clock f = 240e3 cy / dur.
//  - probe_mfma: 48k serial dependent MFMA32 chain, same grid
//                => effective serial cost per dependent MFMA at attn occupancy.
//  - attn x8 internal reps => >300us dispatch, forces rocprof visibility
//                (MfmaUtil/VALUBusy/Occupancy for attn at last).
// All dispatches deterministic & idempotent. Probes write only to d_ws.

typedef float  f32x4  __attribute__((ext_vector_type(4)));
typedef float  f32x16 __attribute__((ext_vector_type(16)));
typedef short  s16x8  __attribute__((ext_vector_type(8)));
typedef short  s16x4  __attribute__((ext_vector_type(4)));

#define MFMA16(A, B, C) __builtin_amdgcn_mfma_f32_16x16x32_bf16((A), (B), (C), 0, 0, 0)
#define MFMA32(A, B, C) __builtin_amdgcn_mfma_f32_32x32x16_bf16((A), (B), (C), 0, 0, 0)

#define GLL16(SRC, DST)                                                              \
    __builtin_amdgcn_global_load_lds(                                                \
        (const __attribute__((address_space(1))) unsigned*)(SRC),                    \
        (__attribute__((address_space(3))) unsigned*)(DST), 16, 0, 0)

static __device__ __forceinline__ ushort f2bf(float f) {
    union { float f; unsigned u; } v; v.f = f;
    unsigned u = v.u;
    unsigned r = (u + 0x7FFFu + ((u >> 16) & 1u)) >> 16;   // RNE
    return (ushort)r;
}

static __device__ __forceinline__ f32x4 fzero() {
    f32x4 v; v[0] = v[1] = v[2] = v[3] = 0.f; return v;
}

// ---------------------------------------------------------------------------
// probe_fma: N=60000 serial dependent FMAs -> dur = N*4cy/f. Writes ws only.
// ---------------------------------------------------------------------------
__global__ __launch_bounds__(256) void probe_fma(float* __restrict__ sink) {
    float a = 1.0f;
    const float b = 1.0000001f, c = 1e-9f;
    #pragma unroll 1
    for (int i = 0; i < 7500; ++i) {
        #pragma unroll
        for (int j = 0; j < 8; ++j) a = __builtin_fmaf(a, b, c);
    }
    sink[blockIdx.x * 256 + threadIdx.x] = a;
}

// ---------------------------------------------------------------------------
// probe_mfma: N=48000 serial dependent MFMA32 -> dur = N*L_eff/f. ws only.
// ---------------------------------------------------------------------------
__global__ __launch_bounds__(256) void probe_mfma(float* __restrict__ sink) {
    s16x8 a;
    #pragma unroll
    for (int j = 0; j < 8; ++j) a[j] = (short)(threadIdx.x + j);
    f32x16 acc;
    #pragma unroll
    for (int r = 0; r < 16; ++r) acc[r] = 0.f;
    #pragma unroll 1
    for (int i = 0; i < 6000; ++i) {
        #pragma unroll
        for (int j = 0; j < 8; ++j) acc = MFMA32(a, a, acc);
    }
    sink[blockIdx.x * 256 + threadIdx.x] = acc[0];
}

// ---------------------------------------------------------------------------
// prep_w: Wt[c][k] = bf16(W*(k,c')), c: 0..63 Q(x0.125), 64..127 K, 128..191 V
// ---------------------------------------------------------------------------
__global__ __launch_bounds__(256) void prep_w(const float* __restrict__ Wq,
                                              const float* __restrict__ Wk,
                                              const float* __restrict__ Wv,
                                              short* __restrict__ Wt) {
    const int blk = blockIdx.x;              // 0..47
    const int mat = blk >> 4, kt = blk & 15;
    const float* src = mat == 0 ? Wq : (mat == 1 ? Wk : Wv);
    const float sc = (mat == 0) ? 0.125f : 1.0f;
    __shared__ float wsm[64][68];
    const int t = threadIdx.x;

    const int rb = t >> 4, c4 = (t & 15) * 4;
    #pragma unroll
    for (int i = 0; i < 4; ++i) {
        f32x4 v = *(const f32x4*)&src[(size_t)(kt * 64 + rb + 16 * i) * 64 + c4];
        *(f32x4*)&wsm[rb + 16 * i][c4] = v;
    }
    __syncthreads();

    const int c = t >> 2, ks = (t & 3) * 16;
    s16x8 o0, o1;
    #pragma unroll
    for (int j = 0; j < 8; ++j) o0[j] = (short)f2bf(wsm[ks + j][c] * sc);
    #pragma unroll
    for (int j = 0; j < 8; ++j) o1[j] = (short)f2bf(wsm[ks + 8 + j][c] * sc);
    const size_t ob = (size_t)(mat * 64 + c) * 1024 + kt * 64 + ks;
    *(s16x8*)&Wt[ob]     = o0;
    *(s16x8*)&Wt[ob + 8] = o1;
}

// ---------------------------------------------------------------------------
// proj: out^T = Wt(192x1024) @ x^T(1024x16-per-block). 1024 blocks x 4 waves.
// ---------------------------------------------------------------------------
__global__ __launch_bounds__(256, 4) void proj(const float* __restrict__ x,
                                               const short* __restrict__ Wt,
                                               const float* __restrict__ bq,
                                               const float* __restrict__ bk,
                                               const float* __restrict__ bv,
                                               short* __restrict__ Qb,
                                               short* __restrict__ Kb,
                                               short* __restrict__ Vt) {
    const int tid  = threadIdx.x;
    const int lane = tid & 63;
    const int w    = tid >> 6;           // 0..3 -> 48-col slice
    const int m0   = blockIdx.x * 16;    // x-row base
    const int l15  = lane & 15, gr = lane >> 4;

    __shared__ short xs[2][16][136];

    const int srow = tid >> 4;           // 0..15
    const int sc16 = (tid & 15) * 4;     // 0..60
    const float* sbase = x + (size_t)(m0 + srow) * 1024 + sc16;

    f32x4 acc[3];
    #pragma unroll
    for (int m = 0; m < 3; ++m) acc[m] = fzero();

    const short* aptr = Wt + (size_t)(48 * w + l15) * 1024 + 8 * gr;

    f32x4 ld[2];
    ld[0] = *(const f32x4*)(sbase);
    ld[1] = *(const f32x4*)(sbase + 64);
    #pragma unroll
    for (int i = 0; i < 2; ++i) {
        s16x4 o;
        #pragma unroll
        for (int j = 0; j < 4; ++j) o[j] = (short)f2bf(ld[i][j]);
        *(s16x4*)&xs[0][srow][sc16 + 64 * i] = o;
    }

    s16x8 a_cur[3], a_nxt[3];
    #pragma unroll
    for (int m = 0; m < 3; ++m) a_cur[m] = *(const s16x8*)(aptr + (size_t)m * 16 * 1024);
    __syncthreads();

    for (int c = 0; c < 8; ++c) {
        const int buf = c & 1;
        if (c < 7) {
            ld[0] = *(const f32x4*)(sbase + 128 * (c + 1));
            ld[1] = *(const f32x4*)(sbase + 128 * (c + 1) + 64);
        }
        #pragma unroll
        for (int f = 0; f < 4; ++f) {
            const int ko = 128 * c + 32 * f;
            const int kn = (ko + 32) & 1023;
            #pragma unroll
            for (int m = 0; m < 3; ++m) a_nxt[m] = *(const s16x8*)(aptr + (size_t)m * 16 * 1024 + kn);
            s16x8 b = *(const s16x8*)&xs[buf][l15][32 * f + 8 * gr];
            #pragma unroll
            for (int m = 0; m < 3; ++m) acc[m] = MFMA16(a_cur[m], b, acc[m]);
            #pragma unroll
            for (int m = 0; m < 3; ++m) a_cur[m] = a_nxt[m];
        }
        if (c < 7) {
            #pragma unroll
            for (int i = 0; i < 2; ++i) {
                s16x4 o;
                #pragma unroll
                for (int j = 0; j < 4; ++j) o[j] = (short)f2bf(ld[i][j]);
                *(s16x4*)&xs[buf ^ 1][srow][sc16 + 64 * i] = o;
            }
        }
        __syncthreads();
    }

    // C: row = W-col = 48w+16m+4gr+r ; col = x-row = m0+l15
    #pragma unroll
    for (int m = 0; m < 3; ++m) {
        const int c0 = 48 * w + 16 * m + 4 * gr;
        const int row = m0 + l15;
        f32x4 v = acc[m];
        if (c0 < 64) {
            s16x4 o;
            #pragma unroll
            for (int r = 0; r < 4; ++r) o[r] = (short)f2bf(v[r] + 0.125f * bq[c0 + r]);
            *(s16x4*)&Qb[(size_t)row * 64 + c0] = o;
        } else if (c0 < 128) {
            s16x4 o;
            #pragma unroll
            for (int r = 0; r < 4; ++r) o[r] = (short)f2bf(v[r] + bk[c0 - 64 + r]);
            *(s16x4*)&Kb[(size_t)row * 64 + (c0 - 64)] = o;
        } else {
            const int b = row >> 12, s = row & 4095;
            #pragma unroll
            for (int r = 0; r < 4; ++r)
                Vt[((size_t)b * 64 + (c0 - 128 + r)) * 4096 + s] =
                    (short)f2bf(v[r] + bv[c0 - 128 + r]);
        }
    }
}

// ---------------------------------------------------------------------------
// attn (R8 logic) with internal x8 repeat for rocprof visibility.
// ---------------------------------------------------------------------------
__global__ __launch_bounds__(256, 3) void attn(const short* __restrict__ Qb,
                                               const short* __restrict__ Kb,
                                               const short* __restrict__ Vt,
                                               float* __restrict__ out) {
    const int bid   = blockIdx.x;                 // 512
    const int xcd   = bid & 7, bi = bid >> 3;
    const int batch = xcd >> 1;                   // one batch per XCD pair
    const int g     = 127 - 2 * bi - (xcd & 1);   // heavy-first, bijective
    const int q0    = g * 32;
    const int tid   = threadIdx.x, lane = tid & 63, w = tid >> 6;
    const int l31   = lane & 31, h = lane >> 5, kb = 4 * h;

    __shared__ __align__(16) char smem[32768];    // 4 waves x (4KB K + 4KB V); Om overlay
    __shared__ float Mm[4][32], Lm[4][32];

    short* lds_k = (short*)(smem + w * 8192);
    short* lds_v = (short*)(smem + w * 8192 + 4096);
    auto kdst = (__attribute__((address_space(3))) char*)smem + w * 8192;
    auto vdst = kdst + 4096;

    const size_t row0 = (size_t)batch * 4096;
    const short* Kb2 = Kb + row0 * 64;
    const short* Vb2 = Vt + (size_t)batch * 64 * 4096;

    const short* Qp = Qb + (row0 + q0 + l31) * 64 + 8 * h;

    const int nt = g + 1;
    const int t0 = (nt * w) >> 2, t1 = (nt * (w + 1)) >> 2;

    auto stage = [&](int j0) {
        #pragma unroll
        for (int i = 0; i < 4; ++i) {
            const int s  = 8 * i + (lane >> 3);
            const int cs = ((lane & 7) ^ (s & 7)) * 8;
            GLL16(Kb2 + (size_t)(j0 + s) * 64 + cs, kdst + i * 1024);
        }
        #pragma unroll
        for (int i = 0; i < 4; ++i) {
            const int d  = 16 * i + (lane >> 2);
            const int cs = ((lane & 3) ^ (d & 3)) * 8;
            GLL16(Vb2 + (size_t)d * 4096 + j0 + cs, vdst + i * 1024);
        }
    };

    #pragma unroll 1
    for (int rep = 0; rep < 8; ++rep) {
        __syncthreads();                          // smem overlay reuse guard

        s16x8 qf[4];
        #pragma unroll
        for (int kk = 0; kk < 4; ++kk) qf[kk] = *(const s16x8*)(Qp + 16 * kk);

        f32x16 oT0, oT1;
        #pragma unroll
        for (int r = 0; r < 16; ++r) { oT0[r] = 0.f; oT1[r] = 0.f; }
        float m = -1e30f, l_ = 0.f;

        if (t0 < t1) stage(t0 * 32);

        for (int t = t0; t < t1; ++t) {
            const int j0 = t * 32;

            // RAW fence: in-flight stage landed
            asm volatile("s_waitcnt vmcnt(0)" ::: "memory");
            __builtin_amdgcn_sched_barrier(0);

            s16x8 kf[4], va[2][2];
            #pragma unroll
            for (int kk = 0; kk < 4; ++kk)
                kf[kk] = *(const s16x8*)(lds_k + l31 * 64 + (((2 * kk + h) ^ (l31 & 7)) * 8));
            #pragma unroll
            for (int dt = 0; dt < 2; ++dt)
                #pragma unroll
                for (int kk = 0; kk < 2; ++kk)
                    va[dt][kk] = *(const s16x8*)(lds_v + (32 * dt + l31) * 32 +
                                                 (((2 * kk + h) ^ (l31 & 3)) * 8));

            // WAR fence: frag data in VGPRs before next DMA
            asm volatile("s_waitcnt lgkmcnt(0)" ::: "memory");
            __builtin_amdgcn_sched_barrier(0);
            if (t + 1 < t1) stage(j0 + 32);

            f32x16 sacc;
            #pragma unroll
            for (int r = 0; r < 16; ++r) sacc[r] = 0.f;
            #pragma unroll
            for (int kk = 0; kk < 4; ++kk) sacc = MFMA32(kf[kk], qf[kk], sacc);

            if (j0 == q0) {
                #pragma unroll
                for (int r = 0; r < 16; ++r) {
                    const int kvloc = (r & 3) + 8 * (r >> 2) + kb;
                    if (kvloc > l31) sacc[r] = -1e30f;
                }
            }

            float tm[8];
            #pragma unroll
            for (int r = 0; r < 8; ++r) tm[r] = fmaxf(sacc[r], sacc[r + 8]);
            #pragma unroll
            for (int r = 0; r < 4; ++r) tm[r] = fmaxf(tm[r], tm[r + 4]);
            tm[0] = fmaxf(fmaxf(tm[0], tm[2]), fmaxf(tm[1], tm[3]));
            float sm = fmaxf(tm[0], __shfl_xor(tm[0], 32));

            if (!__all(sm - m <= 8.f)) {
                const float mn = fmaxf(m, sm);
                const float sc = __expf(m - mn);
                m = mn;
                l_ *= sc;
                #pragma unroll
                for (int r = 0; r < 16; ++r) { oT0[r] *= sc; oT1[r] *= sc; }
            }

            #pragma unroll
            for (int r = 0; r < 16; ++r) sacc[r] = __expf(sacc[r] - m);
            float ts[8];
            #pragma unroll
            for (int r = 0; r < 8; ++r) ts[r] = sacc[r] + sacc[r + 8];
            #pragma unroll
            for (int r = 0; r < 4; ++r) ts[r] = ts[r] + ts[r + 4];
            const float ls = (ts[0] + ts[2]) + (ts[1] + ts[3]);
            l_ += ls + __shfl_xor(ls, 32);

            unsigned pw[8];
            #pragma unroll
            for (int i = 0; i < 8; ++i)
                asm("v_cvt_pk_bf16_f32 %0, %1, %2"
                    : "=v"(pw[i]) : "v"(sacc[2 * i]), "v"(sacc[2 * i + 1]));
            asm volatile("v_permlane32_swap_b32 %0, %1" : "+v"(pw[0]), "+v"(pw[2]));
            asm volatile("v_permlane32_swap_b32 %0, %1" : "+v"(pw[1]), "+v"(pw[3]));
            asm volatile("v_permlane32_swap_b32 %0, %1" : "+v"(pw[4]), "+v"(pw[6]));
            asm volatile("v_permlane32_swap_b32 %0, %1" : "+v"(pw[5]), "+v"(pw[7]));
            union { unsigned u[4]; s16x8 v; } f0, f1;
            f0.u[0] = pw[0]; f0.u[1] = pw[1]; f0.u[2] = pw[2]; f0.u[3] = pw[3];
            f1.u[0] = pw[4]; f1.u[1] = pw[5]; f1.u[2] = pw[6]; f1.u[3] = pw[7];

            oT0 = MFMA32(va[0][0], f0.v, oT0);
            oT0 = MFMA32(va[0][1], f1.v, oT0);
            oT1 = MFMA32(va[1][0], f0.v, oT1);
            oT1 = MFMA32(va[1][1], f1.v, oT1);
        }

        asm volatile("s_waitcnt vmcnt(0)" ::: "memory");
        __builtin_amdgcn_sched_barrier(0);

        float* Om_w = (float*)(smem + w * 8192);  // [32 q][64 d]
        #pragma unroll
        for (int rg = 0; rg < 4; ++rg) {
            f32x4 v0, v1;
            #pragma unroll
            for (int j = 0; j < 4; ++j) { v0[j] = oT0[4 * rg + j]; v1[j] = oT1[4 * rg + j]; }
            const int d0 = rg * 8 + kb;
            *(f32x4*)&Om_w[l31 * 64 + d0]      = v0;
            *(f32x4*)&Om_w[l31 * 64 + 32 + d0] = v1;
        }
        if (lane < 32) { Mm[w][l31] = m; Lm[w][l31] = l_; }
        __syncthreads();

        {
            const int q = tid >> 3, d0 = (tid & 7) * 8;
            const float m0 = Mm[0][q], m1 = Mm[1][q], m2 = Mm[2][q], m3 = Mm[3][q];
            const float mt = fmaxf(fmaxf(m0, m1), fmaxf(m2, m3));
            float sw[4];
            sw[0] = __expf(m0 - mt); sw[1] = __expf(m1 - mt);
            sw[2] = __expf(m2 - mt); sw[3] = __expf(m3 - mt);
            const float lt = sw[0] * Lm[0][q] + sw[1] * Lm[1][q] + sw[2] * Lm[2][q] + sw[3] * Lm[3][q];
            const float inv = 1.f / lt;
            f32x4 a0 = fzero(), a1 = fzero();
            #pragma unroll
            for (int ww = 0; ww < 4; ++ww) {
                const float* Om_r = (const float*)(smem + ww * 8192);
                f32x4 u0 = *(const f32x4*)&Om_r[q * 64 + d0];
                f32x4 u1 = *(const f32x4*)&Om_r[q * 64 + d0 + 4];
                #pragma unroll
                for (int j = 0; j < 4; ++j) { a0[j] += sw[ww] * u0[j]; a1[j] += sw[ww] * u1[j]; }
            }
            const size_t ob = (row0 + q0 + q) * 64 + d0;
            f32x4 r0, r1;
            #pragma unroll
            for (int j = 0; j < 4; ++j) { r0[j] = a0[j] * inv; r1[j] = a1[j] * inv; }
            *(f32x4*)&out[ob]     = r0;
            *(f32x4*)&out[ob + 4] = r1;
        }
    }
}

// ---------------------------------------------------------------------------
extern "C" void kernel_launch(void* const* d_in, const int* in_sizes, int n_in,
                              void* d_out, int out_size, void* d_ws, size_t ws_size,
                              hipStream_t stream) {
    const float* x  = (const float*)d_in[0];
    const float* Wq = (const float*)d_in[2];
    const float* bq = (const float*)d_in[3];
    const float* Wk = (const float*)d_in[4];
    const float* bk = (const float*)d_in[5];
    const float* Wv = (const float*)d_in[6];
    const float* bv = (const float*)d_in[7];
    float* out = (float*)d_out;

    char* ws = (char*)d_ws;
    short* Wt = (short*)(ws);
    short* Qb = (short*)(ws + 393216);
    short* Kb = (short*)(ws + 2490368);
    short* Vt = (short*)(ws + 4587520);
    float* sink1 = (float*)(ws + (16u << 20));
    float* sink2 = (float*)(ws + (17u << 20));

    prep_w<<<dim3(48), dim3(256), 0, stream>>>(Wq, Wk, Wv, Wt);
    proj<<<dim3(1024), dim3(256), 0, stream>>>(x, Wt, bq, bk, bv, Qb, Kb, Vt);
    attn<<<dim3(512), dim3(256), 0, stream>>>(Qb, Kb, Vt, out);
    probe_fma<<<dim3(512), dim3(256), 0, stream>>>(sink1);
    probe_mfma<<<dim3(512), dim3(256), 0, stream>>>(sink2);
}

// Round 11
// 86.454 us; speedup vs baseline: 20.7705x; 20.7705x over previous
//
#include <hip/hip_runtime.h>
#include <hip/hip_bf16.h>

// Self-attention head, B=4 S=4096 Dm=1024 Dk=64, fp32 in/out, bf16 MFMA inside.
// R11: ILP round (calibration: core ~1.34 GHz, dependent MFMA32 ~43 cy).
//  - attn: 2 independent KV streams per wave, phase-interleaved; in-register
//    LSE merge. One vmcnt(0) per pair. 2 blocks/CU (64KB LDS + 1KB).
//  - proj: depth-2 global prefetch (chunk c+3 in flight), unrolled.

typedef float  f32x4  __attribute__((ext_vector_type(4)));
typedef float  f32x16 __attribute__((ext_vector_type(16)));
typedef short  s16x8  __attribute__((ext_vector_type(8)));
typedef short  s16x4  __attribute__((ext_vector_type(4)));

#define MFMA16(A, B, C) __builtin_amdgcn_mfma_f32_16x16x32_bf16((A), (B), (C), 0, 0, 0)
#define MFMA32(A, B, C) __builtin_amdgcn_mfma_f32_32x32x16_bf16((A), (B), (C), 0, 0, 0)

#define GLL16(SRC, DST)                                                              \
    __builtin_amdgcn_global_load_lds(                                                \
        (const __attribute__((address_space(1))) unsigned*)(SRC),                    \
        (__attribute__((address_space(3))) unsigned*)(DST), 16, 0, 0)

static __device__ __forceinline__ ushort f2bf(float f) {
    union { float f; unsigned u; } v; v.f = f;
    unsigned u = v.u;
    unsigned r = (u + 0x7FFFu + ((u >> 16) & 1u)) >> 16;   // RNE
    return (ushort)r;
}

static __device__ __forceinline__ f32x4 fzero() {
    f32x4 v; v[0] = v[1] = v[2] = v[3] = 0.f; return v;
}

// ---------------------------------------------------------------------------
// prep_w: Wt[c][k] = bf16(W*(k,c')), c: 0..63 Q(x0.125), 64..127 K, 128..191 V
// ---------------------------------------------------------------------------
__global__ __launch_bounds__(256) void prep_w(const float* __restrict__ Wq,
                                              const float* __restrict__ Wk,
                                              const float* __restrict__ Wv,
                                              short* __restrict__ Wt) {
    const int blk = blockIdx.x;              // 0..47
    const int mat = blk >> 4, kt = blk & 15;
    const float* src = mat == 0 ? Wq : (mat == 1 ? Wk : Wv);
    const float sc = (mat == 0) ? 0.125f : 1.0f;
    __shared__ float wsm[64][68];
    const int t = threadIdx.x;

    const int rb = t >> 4, c4 = (t & 15) * 4;
    #pragma unroll
    for (int i = 0; i < 4; ++i) {
        f32x4 v = *(const f32x4*)&src[(size_t)(kt * 64 + rb + 16 * i) * 64 + c4];
        *(f32x4*)&wsm[rb + 16 * i][c4] = v;
    }
    __syncthreads();

    const int c = t >> 2, ks = (t & 3) * 16;
    s16x8 o0, o1;
    #pragma unroll
    for (int j = 0; j < 8; ++j) o0[j] = (short)f2bf(wsm[ks + j][c] * sc);
    #pragma unroll
    for (int j = 0; j < 8; ++j) o1[j] = (short)f2bf(wsm[ks + 8 + j][c] * sc);
    const size_t ob = (size_t)(mat * 64 + c) * 1024 + kt * 64 + ks;
    *(s16x8*)&Wt[ob]     = o0;
    *(s16x8*)&Wt[ob + 8] = o1;
}

// ---------------------------------------------------------------------------
// proj: out^T = Wt(192x1024) @ x^T(1024x16-per-block). 1024 blocks x 4 waves.
// Depth-2 x prefetch: chunk c+3 issued at iter c (two reg sets, unrolled).
// ---------------------------------------------------------------------------
__global__ __launch_bounds__(256, 4) void proj(const float* __restrict__ x,
                                               const short* __restrict__ Wt,
                                               const float* __restrict__ bq,
                                               const float* __restrict__ bk,
                                               const float* __restrict__ bv,
                                               short* __restrict__ Qb,
                                               short* __restrict__ Kb,
                                               short* __restrict__ Vt) {
    const int tid  = threadIdx.x;
    const int lane = tid & 63;
    const int w    = tid >> 6;           // 0..3 -> 48-col slice
    const int m0   = blockIdx.x * 16;    // x-row base
    const int l15  = lane & 15, gr = lane >> 4;

    __shared__ short xs[2][16][136];

    const int srow = tid >> 4;           // 0..15
    const int sc16 = (tid & 15) * 4;     // 0..60
    const float* sbase = x + (size_t)(m0 + srow) * 1024 + sc16;

    f32x4 acc[3];
    #pragma unroll
    for (int m = 0; m < 3; ++m) acc[m] = fzero();

    const short* aptr = Wt + (size_t)(48 * w + l15) * 1024 + 8 * gr;

    // prologue: chunk0 -> LDS; chunk1 (ldp[1]) and chunk2 (ldp[0]) in flight
    f32x4 ldp[2][2];
    {
        f32x4 c0a = *(const f32x4*)(sbase);
        f32x4 c0b = *(const f32x4*)(sbase + 64);
        s16x4 o;
        #pragma unroll
        for (int j = 0; j < 4; ++j) o[j] = (short)f2bf(c0a[j]);
        *(s16x4*)&xs[0][srow][sc16] = o;
        #pragma unroll
        for (int j = 0; j < 4; ++j) o[j] = (short)f2bf(c0b[j]);
        *(s16x4*)&xs[0][srow][sc16 + 64] = o;
    }
    ldp[1][0] = *(const f32x4*)(sbase + 128);
    ldp[1][1] = *(const f32x4*)(sbase + 128 + 64);
    ldp[0][0] = *(const f32x4*)(sbase + 256);
    ldp[0][1] = *(const f32x4*)(sbase + 256 + 64);

    s16x8 a_cur[3], a_nxt[3];
    #pragma unroll
    for (int m = 0; m < 3; ++m) a_cur[m] = *(const s16x8*)(aptr + (size_t)m * 16 * 1024);
    __syncthreads();

    #pragma unroll
    for (int c = 0; c < 8; ++c) {
        #pragma unroll
        for (int f = 0; f < 4; ++f) {
            const int ko = 128 * c + 32 * f;
            const int kn = (ko + 32) & 1023;
            #pragma unroll
            for (int m = 0; m < 3; ++m) a_nxt[m] = *(const s16x8*)(aptr + (size_t)m * 16 * 1024 + kn);
            s16x8 b = *(const s16x8*)&xs[c & 1][l15][32 * f + 8 * gr];
            #pragma unroll
            for (int m = 0; m < 3; ++m) acc[m] = MFMA16(a_cur[m], b, acc[m]);
            #pragma unroll
            for (int m = 0; m < 3; ++m) a_cur[m] = a_nxt[m];
        }
        if (c < 7) {
            // write chunk c+1 (in ldp[(c+1)&1]) to the other LDS buffer
            s16x4 o;
            #pragma unroll
            for (int j = 0; j < 4; ++j) o[j] = (short)f2bf(ldp[(c + 1) & 1][0][j]);
            *(s16x4*)&xs[(c + 1) & 1][srow][sc16] = o;
            #pragma unroll
            for (int j = 0; j < 4; ++j) o[j] = (short)f2bf(ldp[(c + 1) & 1][1][j]);
            *(s16x4*)&xs[(c + 1) & 1][srow][sc16 + 64] = o;
        }
        if (c < 5) {
            // issue chunk c+3 into the set just freed
            ldp[(c + 1) & 1][0] = *(const f32x4*)(sbase + 128 * (c + 3));
            ldp[(c + 1) & 1][1] = *(const f32x4*)(sbase + 128 * (c + 3) + 64);
        }
        __syncthreads();
    }

    // C: row = W-col = 48w+16m+4gr+r ; col = x-row = m0+l15
    #pragma unroll
    for (int m = 0; m < 3; ++m) {
        const int c0 = 48 * w + 16 * m + 4 * gr;
        const int row = m0 + l15;
        f32x4 v = acc[m];
        if (c0 < 64) {
            s16x4 o;
            #pragma unroll
            for (int r = 0; r < 4; ++r) o[r] = (short)f2bf(v[r] + 0.125f * bq[c0 + r]);
            *(s16x4*)&Qb[(size_t)row * 64 + c0] = o;
        } else if (c0 < 128) {
            s16x4 o;
            #pragma unroll
            for (int r = 0; r < 4; ++r) o[r] = (short)f2bf(v[r] + bk[c0 - 64 + r]);
            *(s16x4*)&Kb[(size_t)row * 64 + (c0 - 64)] = o;
        } else {
            const int b = row >> 12, s = row & 4095;
            #pragma unroll
            for (int r = 0; r < 4; ++r)
                Vt[((size_t)b * 64 + (c0 - 128 + r)) * 4096 + s] =
                    (short)f2bf(v[r] + bv[c0 - 128 + r]);
        }
    }
}

// ---------------------------------------------------------------------------
// attn: 32x32 swapped-operand S^T, in-register softmax. TWO independent KV
// streams per wave (A/B halves of the causal range), own LDS buffers and
// (m,l,O) state, phase-interleaved so dependent chains overlap; in-register
// LSE merge at the end. DMA staging with RAW vmcnt(0) per pair + WAR lgkmcnt.
// ---------------------------------------------------------------------------
__global__ __launch_bounds__(256, 2) void attn(const short* __restrict__ Qb,
                                               const short* __restrict__ Kb,
                                               const short* __restrict__ Vt,
                                               float* __restrict__ out) {
    const int bid   = blockIdx.x;                 // 512
    const int xcd   = bid & 7, bi = bid >> 3;
    const int batch = xcd >> 1;                   // one batch per XCD pair
    const int g     = 127 - 2 * bi - (xcd & 1);   // heavy-first, bijective
    const int q0    = g * 32;
    const int tid   = threadIdx.x, lane = tid & 63, w = tid >> 6;
    const int l31   = lane & 31, h = lane >> 5, kb = 4 * h;

    __shared__ __align__(16) char smem[65536];    // wave w: A @ w*16K, B @ +8K
    __shared__ float Mm[4][32], Lm[4][32];

    char* baseA = smem + w * 16384;
    char* baseB = baseA + 8192;
    short* ldsKA = (short*)baseA;        short* ldsVA = (short*)(baseA + 4096);
    short* ldsKB = (short*)baseB;        short* ldsVB = (short*)(baseB + 4096);

    const size_t row0 = (size_t)batch * 4096;
    const short* Kb2 = Kb + row0 * 64;
    const short* Vb2 = Vt + (size_t)batch * 64 * 4096;

    const short* Qp = Qb + (row0 + q0 + l31) * 64 + 8 * h;
    s16x8 qf[4];
    #pragma unroll
    for (int kk = 0; kk < 4; ++kk) qf[kk] = *(const s16x8*)(Qp + 16 * kk);

    f32x16 oT0A, oT1A, oT0B, oT1B;
    #pragma unroll
    for (int r = 0; r < 16; ++r) { oT0A[r] = 0.f; oT1A[r] = 0.f; oT0B[r] = 0.f; oT1B[r] = 0.f; }
    float mA = -1e30f, lA = 0.f, mB = -1e30f, lB = 0.f;

    const int nt = g + 1;
    const int t0 = (nt * w) >> 2, t1 = (nt * (w + 1)) >> 2;
    const int n  = t1 - t0;
    const int nA = (n + 1) >> 1, nB = n >> 1;
    const int tB0 = t0 + nA;

    auto stage = [&](int j0, char* base) {
        auto kdst = (__attribute__((address_space(3))) char*)base;
        auto vdst = kdst + 4096;
        #pragma unroll
        for (int i = 0; i < 4; ++i) {
            const int s  = 8 * i + (lane >> 3);
            const int cs = ((lane & 7) ^ (s & 7)) * 8;
            GLL16(Kb2 + (size_t)(j0 + s) * 64 + cs, kdst + i * 1024);
        }
        #pragma unroll
        for (int i = 0; i < 4; ++i) {
            const int d  = 16 * i + (lane >> 2);
            const int cs = ((lane & 3) ^ (d & 3)) * 8;
            GLL16(Vb2 + (size_t)d * 4096 + j0 + cs, vdst + i * 1024);
        }
    };

    if (nA > 0) stage(t0 * 32, baseA);
    if (nB > 0) stage(tB0 * 32, baseB);

    // ---------- paired steps ----------
    for (int i = 0; i < nB; ++i) {
        const int jA = (t0 + i) * 32, jB = (tB0 + i) * 32;

        asm volatile("s_waitcnt vmcnt(0)" ::: "memory");   // RAW: both tiles landed
        __builtin_amdgcn_sched_barrier(0);

        s16x8 kfA[4], vaA[2][2], kfB[4], vaB[2][2];
        #pragma unroll
        for (int kk = 0; kk < 4; ++kk) {
            const int off = ((2 * kk + h) ^ (l31 & 7)) * 8;
            kfA[kk] = *(const s16x8*)(ldsKA + l31 * 64 + off);
            kfB[kk] = *(const s16x8*)(ldsKB + l31 * 64 + off);
        }
        #pragma unroll
        for (int dt = 0; dt < 2; ++dt)
            #pragma unroll
            for (int kk = 0; kk < 2; ++kk) {
                const int off = (32 * dt + l31) * 32 + (((2 * kk + h) ^ (l31 & 3)) * 8);
                vaA[dt][kk] = *(const s16x8*)(ldsVA + off);
                vaB[dt][kk] = *(const s16x8*)(ldsVB + off);
            }

        asm volatile("s_waitcnt lgkmcnt(0)" ::: "memory"); // WAR: frags in VGPRs
        __builtin_amdgcn_sched_barrier(0);
        if (i + 1 < nA) stage((t0 + i + 1) * 32, baseA);
        if (i + 1 < nB) stage((tB0 + i + 1) * 32, baseB);

        // QK interleaved: two independent 4-deep chains
        f32x16 sA, sB;
        #pragma unroll
        for (int r = 0; r < 16; ++r) { sA[r] = 0.f; sB[r] = 0.f; }
        #pragma unroll
        for (int kk = 0; kk < 4; ++kk) {
            sA = MFMA32(kfA[kk], qf[kk], sA);
            sB = MFMA32(kfB[kk], qf[kk], sB);
        }

        if (jA == q0) {
            #pragma unroll
            for (int r = 0; r < 16; ++r) {
                const int kvloc = (r & 3) + 8 * (r >> 2) + kb;
                if (kvloc > l31) sA[r] = -1e30f;
            }
        }
        if (jB == q0) {
            #pragma unroll
            for (int r = 0; r < 16; ++r) {
                const int kvloc = (r & 3) + 8 * (r >> 2) + kb;
                if (kvloc > l31) sB[r] = -1e30f;
            }
        }

        // row-max trees (independent)
        float tmA[8], tmB[8];
        #pragma unroll
        for (int r = 0; r < 8; ++r) { tmA[r] = fmaxf(sA[r], sA[r + 8]); tmB[r] = fmaxf(sB[r], sB[r + 8]); }
        #pragma unroll
        for (int r = 0; r < 4; ++r) { tmA[r] = fmaxf(tmA[r], tmA[r + 4]); tmB[r] = fmaxf(tmB[r], tmB[r + 4]); }
        tmA[0] = fmaxf(fmaxf(tmA[0], tmA[2]), fmaxf(tmA[1], tmA[3]));
        tmB[0] = fmaxf(fmaxf(tmB[0], tmB[2]), fmaxf(tmB[1], tmB[3]));
        const float shA = __shfl_xor(tmA[0], 32);
        const float shB = __shfl_xor(tmB[0], 32);
        const float smA = fmaxf(tmA[0], shA);
        const float smB = fmaxf(tmB[0], shB);

        if (!__all(smA - mA <= 8.f)) {
            const float mn = fmaxf(mA, smA);
            const float sc = __expf(mA - mn);
            mA = mn; lA *= sc;
            #pragma unroll
            for (int r = 0; r < 16; ++r) { oT0A[r] *= sc; oT1A[r] *= sc; }
        }
        if (!__all(smB - mB <= 8.f)) {
            const float mn = fmaxf(mB, smB);
            const float sc = __expf(mB - mn);
            mB = mn; lB *= sc;
            #pragma unroll
            for (int r = 0; r < 16; ++r) { oT0B[r] *= sc; oT1B[r] *= sc; }
        }

        #pragma unroll
        for (int r = 0; r < 16; ++r) { sA[r] = __expf(sA[r] - mA); sB[r] = __expf(sB[r] - mB); }

        float tsA[8], tsB[8];
        #pragma unroll
        for (int r = 0; r < 8; ++r) { tsA[r] = sA[r] + sA[r + 8]; tsB[r] = sB[r] + sB[r + 8]; }
        #pragma unroll
        for (int r = 0; r < 4; ++r) { tsA[r] = tsA[r] + tsA[r + 4]; tsB[r] = tsB[r] + tsB[r + 4]; }
        const float lsA = (tsA[0] + tsA[2]) + (tsA[1] + tsA[3]);
        const float lsB = (tsB[0] + tsB[2]) + (tsB[1] + tsB[3]);
        const float lxA = __shfl_xor(lsA, 32);
        const float lxB = __shfl_xor(lsB, 32);
        lA += lsA + lxA;
        lB += lsB + lxB;

        unsigned pwA[8], pwB[8];
        #pragma unroll
        for (int i2 = 0; i2 < 8; ++i2) {
            asm("v_cvt_pk_bf16_f32 %0, %1, %2" : "=v"(pwA[i2]) : "v"(sA[2 * i2]), "v"(sA[2 * i2 + 1]));
            asm("v_cvt_pk_bf16_f32 %0, %1, %2" : "=v"(pwB[i2]) : "v"(sB[2 * i2]), "v"(sB[2 * i2 + 1]));
        }
        asm volatile("v_permlane32_swap_b32 %0, %1" : "+v"(pwA[0]), "+v"(pwA[2]));
        asm volatile("v_permlane32_swap_b32 %0, %1" : "+v"(pwB[0]), "+v"(pwB[2]));
        asm volatile("v_permlane32_swap_b32 %0, %1" : "+v"(pwA[1]), "+v"(pwA[3]));
        asm volatile("v_permlane32_swap_b32 %0, %1" : "+v"(pwB[1]), "+v"(pwB[3]));
        asm volatile("v_permlane32_swap_b32 %0, %1" : "+v"(pwA[4]), "+v"(pwA[6]));
        asm volatile("v_permlane32_swap_b32 %0, %1" : "+v"(pwB[4]), "+v"(pwB[6]));
        asm volatile("v_permlane32_swap_b32 %0, %1" : "+v"(pwA[5]), "+v"(pwA[7]));
        asm volatile("v_permlane32_swap_b32 %0, %1" : "+v"(pwB[5]), "+v"(pwB[7]));
        union { unsigned u[4]; s16x8 v; } f0A, f1A, f0B, f1B;
        f0A.u[0] = pwA[0]; f0A.u[1] = pwA[1]; f0A.u[2] = pwA[2]; f0A.u[3] = pwA[3];
        f1A.u[0] = pwA[4]; f1A.u[1] = pwA[5]; f1A.u[2] = pwA[6]; f1A.u[3] = pwA[7];
        f0B.u[0] = pwB[0]; f0B.u[1] = pwB[1]; f0B.u[2] = pwB[2]; f0B.u[3] = pwB[3];
        f1B.u[0] = pwB[4]; f1B.u[1] = pwB[5]; f1B.u[2] = pwB[6]; f1B.u[3] = pwB[7];

        // PV: four independent accumulator chains, interleaved
        oT0A = MFMA32(vaA[0][0], f0A.v, oT0A);
        oT0B = MFMA32(vaB[0][0], f0B.v, oT0B);
        oT1A = MFMA32(vaA[1][0], f0A.v, oT1A);
        oT1B = MFMA32(vaB[1][0], f0B.v, oT1B);
        oT0A = MFMA32(vaA[0][1], f1A.v, oT0A);
        oT0B = MFMA32(vaB[0][1], f1B.v, oT0B);
        oT1A = MFMA32(vaA[1][1], f1A.v, oT1A);
        oT1B = MFMA32(vaB[1][1], f1B.v, oT1B);
    }

    // ---------- A-only epilogue (n odd) ----------
    if (nA > nB) {
        const int jA = (t0 + nB) * 32;
        asm volatile("s_waitcnt vmcnt(0)" ::: "memory");
        __builtin_amdgcn_sched_barrier(0);

        s16x8 kfA[4], vaA[2][2];
        #pragma unroll
        for (int kk = 0; kk < 4; ++kk)
            kfA[kk] = *(const s16x8*)(ldsKA + l31 * 64 + (((2 * kk + h) ^ (l31 & 7)) * 8));
        #pragma unroll
        for (int dt = 0; dt < 2; ++dt)
            #pragma unroll
            for (int kk = 0; kk < 2; ++kk)
                vaA[dt][kk] = *(const s16x8*)(ldsVA + (32 * dt + l31) * 32 +
                                              (((2 * kk + h) ^ (l31 & 3)) * 8));

        f32x16 sA;
        #pragma unroll
        for (int r = 0; r < 16; ++r) sA[r] = 0.f;
        #pragma unroll
        for (int kk = 0; kk < 4; ++kk) sA = MFMA32(kfA[kk], qf[kk], sA);

        if (jA == q0) {
            #pragma unroll
            for (int r = 0; r < 16; ++r) {
                const int kvloc = (r & 3) + 8 * (r >> 2) + kb;
                if (kvloc > l31) sA[r] = -1e30f;
            }
        }

        float tm[8];
        #pragma unroll
        for (int r = 0; r < 8; ++r) tm[r] = fmaxf(sA[r], sA[r + 8]);
        #pragma unroll
        for (int r = 0; r < 4; ++r) tm[r] = fmaxf(tm[r], tm[r + 4]);
        tm[0] = fmaxf(fmaxf(tm[0], tm[2]), fmaxf(tm[1], tm[3]));
        const float sm = fmaxf(tm[0], __shfl_xor(tm[0], 32));

        if (!__all(sm - mA <= 8.f)) {
            const float mn = fmaxf(mA, sm);
            const float sc = __expf(mA - mn);
            mA = mn; lA *= sc;
            #pragma unroll
            for (int r = 0; r < 16; ++r) { oT0A[r] *= sc; oT1A[r] *= sc; }
        }
        #pragma unroll
        for (int r = 0; r < 16; ++r) sA[r] = __expf(sA[r] - mA);
        float ts[8];
        #pragma unroll
        for (int r = 0; r < 8; ++r) ts[r] = sA[r] + sA[r + 8];
        #pragma unroll
        for (int r = 0; r < 4; ++r) ts[r] = ts[r] + ts[r + 4];
        const float ls = (ts[0] + ts[2]) + (ts[1] + ts[3]);
        lA += ls + __shfl_xor(ls, 32);

        unsigned pw[8];
        #pragma unroll
        for (int i2 = 0; i2 < 8; ++i2)
            asm("v_cvt_pk_bf16_f32 %0, %1, %2" : "=v"(pw[i2]) : "v"(sA[2 * i2]), "v"(sA[2 * i2 + 1]));
        asm volatile("v_permlane32_swap_b32 %0, %1" : "+v"(pw[0]), "+v"(pw[2]));
        asm volatile("v_permlane32_swap_b32 %0, %1" : "+v"(pw[1]), "+v"(pw[3]));
        asm volatile("v_permlane32_swap_b32 %0, %1" : "+v"(pw[4]), "+v"(pw[6]));
        asm volatile("v_permlane32_swap_b32 %0, %1" : "+v"(pw[5]), "+v"(pw[7]));
        union { unsigned u[4]; s16x8 v; } f0, f1;
        f0.u[0] = pw[0]; f0.u[1] = pw[1]; f0.u[2] = pw[2]; f0.u[3] = pw[3];
        f1.u[0] = pw[4]; f1.u[1] = pw[5]; f1.u[2] = pw[6]; f1.u[3] = pw[7];

        oT0A = MFMA32(vaA[0][0], f0.v, oT0A);
        oT1A = MFMA32(vaA[1][0], f0.v, oT1A);
        oT0A = MFMA32(vaA[0][1], f1.v, oT0A);
        oT1A = MFMA32(vaA[1][1], f1.v, oT1A);
    }

    // ---------- in-register LSE merge of streams A and B ----------
    const float mT = fmaxf(mA, mB);
    const float eA = __expf(mA - mT), eB = __expf(mB - mT);
    const float lT = eA * lA + eB * lB;
    #pragma unroll
    for (int r = 0; r < 16; ++r) {
        oT0A[r] = eA * oT0A[r] + eB * oT0B[r];
        oT1A[r] = eA * oT1A[r] + eB * oT1B[r];
    }

    asm volatile("s_waitcnt vmcnt(0)" ::: "memory");
    __builtin_amdgcn_sched_barrier(0);

    // publish partials into this wave's own (dead) A staging region
    float* Om_w = (float*)(smem + w * 16384);     // [32 q][64 d]
    #pragma unroll
    for (int rg = 0; rg < 4; ++rg) {
        f32x4 v0, v1;
        #pragma unroll
        for (int j = 0; j < 4; ++j) { v0[j] = oT0A[4 * rg + j]; v1[j] = oT1A[4 * rg + j]; }
        const int d0 = rg * 8 + kb;
        *(f32x4*)&Om_w[l31 * 64 + d0]      = v0;
        *(f32x4*)&Om_w[l31 * 64 + 32 + d0] = v1;
    }
    if (lane < 32) { Mm[w][l31] = mT; Lm[w][l31] = lT; }
    __syncthreads();

    // merge 4 KV-split wave partials: 256 threads = 32 q x 8 d-groups
    {
        const int q = tid >> 3, d0 = (tid & 7) * 8;
        const float m0 = Mm[0][q], m1 = Mm[1][q], m2 = Mm[2][q], m3 = Mm[3][q];
        const float mt = fmaxf(fmaxf(m0, m1), fmaxf(m2, m3));
        float sw[4];
        sw[0] = __expf(m0 - mt); sw[1] = __expf(m1 - mt);
        sw[2] = __expf(m2 - mt); sw[3] = __expf(m3 - mt);
        const float lt = sw[0] * Lm[0][q] + sw[1] * Lm[1][q] + sw[2] * Lm[2][q] + sw[3] * Lm[3][q];
        const float inv = 1.f / lt;
        f32x4 a0 = fzero(), a1 = fzero();
        #pragma unroll
        for (int ww = 0; ww < 4; ++ww) {
            const float* Om_r = (const float*)(smem + ww * 16384);
            f32x4 u0 = *(const f32x4*)&Om_r[q * 64 + d0];
            f32x4 u1 = *(const f32x4*)&Om_r[q * 64 + d0 + 4];
            #pragma unroll
            for (int j = 0; j < 4; ++j) { a0[j] += sw[ww] * u0[j]; a1[j] += sw[ww] * u1[j]; }
        }
        const size_t ob = (row0 + q0 + q) * 64 + d0;
        f32x4 r0, r1;
        #pragma unroll
        for (int j = 0; j < 4; ++j) { r0[j] = a0[j] * inv; r1[j] = a1[j] * inv; }
        *(f32x4*)&out[ob]     = r0;
        *(f32x4*)&out[ob + 4] = r1;
    }
}

// ---------------------------------------------------------------------------
extern "C" void kernel_launch(void* const* d_in, const int* in_sizes, int n_in,
                              void* d_out, int out_size, void* d_ws, size_t ws_size,
                              hipStream_t stream) {
    const float* x  = (const float*)d_in[0];
    // d_in[1] (mask) is the causal tril by construction; implemented analytically.
    const float* Wq = (const float*)d_in[2];
    const float* bq = (const float*)d_in[3];
    const float* Wk = (const float*)d_in[4];
    const float* bk = (const float*)d_in[5];
    const float* Wv = (const float*)d_in[6];
    const float* bv = (const float*)d_in[7];
    float* out = (float*)d_out;

    char* ws = (char*)d_ws;
    short* Wt = (short*)(ws);                    // 192*1024*2 = 393216 B
    short* Qb = (short*)(ws + 393216);           // 2 MiB
    short* Kb = (short*)(ws + 2490368);          // 2 MiB
    short* Vt = (short*)(ws + 4587520);          // [4][64][4096] = 2 MiB

    prep_w<<<dim3(48),   dim3(256), 0, stream>>>(Wq, Wk, Wv, Wt);
    proj<<<dim3(1024),   dim3(256), 0, stream>>>(x, Wt, bq, bk, bv, Qb, Kb, Vt);
    attn<<<dim3(512),    dim3(256), 0, stream>>>(Qb, Kb, Vt, out);
}